// Round 3
// baseline (476.197 us; speedup 1.0000x reference)
//
#include <hip/hip_runtime.h>
#include <hip/hip_bf16.h>
#include <stdint.h>

typedef __bf16 bf16;
typedef short short8 __attribute__((ext_vector_type(8)));   // bf16 A/B frag (bit pattern)
typedef float f32x4 __attribute__((ext_vector_type(4)));

#define LOG2E 1.4426950408889634f

union V16 { uint4 u; short8 s; bf16 h[8]; };
union U8  { ushort4 s; bf16 h[4]; };

// ---- kernel 0: f32 -> bf16 bulk convert (n multiple of 8) ---------------
__global__ __launch_bounds__(256) void k_cvt(const float* __restrict__ src,
                                             bf16* __restrict__ dst, long long n) {
  long long i = ((long long)blockIdx.x * 256 + threadIdx.x) * 8;
  if (i >= n) return;
  float4 a = *(const float4*)(src + i);
  float4 b = *(const float4*)(src + i + 4);
  U8 w0, w1;
  w0.h[0] = (bf16)a.x; w0.h[1] = (bf16)a.y; w0.h[2] = (bf16)a.z; w0.h[3] = (bf16)a.w;
  w1.h[0] = (bf16)b.x; w1.h[1] = (bf16)b.y; w1.h[2] = (bf16)b.z; w1.h[3] = (bf16)b.w;
  *(ushort4*)(dst + i)     = w0.s;
  *(ushort4*)(dst + i + 4) = w1.s;
}

// ---- kernel 1: pack adjacency rows into 512-bit masks (ballot trick) ----
__global__ __launch_bounds__(256) void k_maskpack(const int* __restrict__ adj,
                                                  unsigned long long* __restrict__ mask) {
  int wid = blockIdx.x * 4 + (threadIdx.x >> 6);
  int lane = threadIdx.x & 63;
  int a = adj[(long long)wid * 64 + lane];
  unsigned long long m = __ballot(a > 0);
  if (lane == 0) mask[wid] = m;
}

// ---- kernel 2: f32 [R,C] -> bf16 [C,R] transpose+convert per z-slice ----
__global__ __launch_bounds__(256) void k_transpose(const float* __restrict__ src,
                                                   bf16* __restrict__ dst, int R, int C) {
  __shared__ float t[32][33];
  int c0 = blockIdx.x * 32, r0 = blockIdx.y * 32;
  src += (long long)blockIdx.z * R * C;
  dst += (long long)blockIdx.z * R * C;
  int tx = threadIdx.x & 31, ty = threadIdx.x >> 5;
  for (int rr = ty; rr < 32; rr += 8)
    t[rr][tx] = src[(long long)(r0 + rr) * C + (c0 + tx)];
  __syncthreads();
  for (int cc = ty; cc < 32; cc += 8)
    dst[(long long)(c0 + cc) * R + (r0 + tx)] = (bf16)t[tx][cc];
}

// ---- kernel 3: bf16 MFMA GEMM, transposed output ------------------------
// outT[(h*32+b)*256 + f][i] = sum_k A[m=b*512+i][k] * WT[h][f][k]
__global__ __launch_bounds__(256) void k_gemm(const bf16* __restrict__ A,
                                              const bf16* __restrict__ WT,
                                              bf16* __restrict__ outT, int K) {
  constexpr int PK = 40;
  __shared__ bf16 As[128 * PK];
  __shared__ bf16 Bs[128 * PK];
  const int nb = blockIdx.x, mb = blockIdx.y, h = blockIdx.z;
  const int tid = threadIdx.x, wave = tid >> 6, lane = tid & 63;
  const int lrow = lane & 15, quad = lane >> 4;
  const long long mbase = (long long)mb * 128;
  const int nbase = nb * 128;
  const bf16* W = WT + (long long)h * 256 * K;
  const int wm = (wave >> 1) * 64, wn = (wave & 1) * 64;
  const int srow = tid >> 1, skoff = (tid & 1) * 16;
  const bf16* ag = A + (mbase + srow) * K + skoff;
  const bf16* bg = W + (long long)(nbase + srow) * K + skoff;
  f32x4 acc[4][4];
#pragma unroll
  for (int i = 0; i < 4; i++)
#pragma unroll
    for (int j = 0; j < 4; j++) acc[i][j] = {0.f, 0.f, 0.f, 0.f};
  for (int k0 = 0; k0 < K; k0 += 32) {
    uint4 a0 = *(const uint4*)(ag + k0);
    uint4 a1 = *(const uint4*)(ag + k0 + 8);
    uint4 b0 = *(const uint4*)(bg + k0);
    uint4 b1 = *(const uint4*)(bg + k0 + 8);
    __syncthreads();
    *(uint4*)(As + srow * PK + skoff)     = a0;
    *(uint4*)(As + srow * PK + skoff + 8) = a1;
    *(uint4*)(Bs + srow * PK + skoff)     = b0;
    *(uint4*)(Bs + srow * PK + skoff + 8) = b1;
    __syncthreads();
    V16 af[4], bfx[4];
#pragma unroll
    for (int mi = 0; mi < 4; mi++)
      af[mi].u = *(const uint4*)(As + (wm + mi * 16 + lrow) * PK + quad * 8);
#pragma unroll
    for (int ni = 0; ni < 4; ni++)
      bfx[ni].u = *(const uint4*)(Bs + (wn + ni * 16 + lrow) * PK + quad * 8);
#pragma unroll
    for (int mi = 0; mi < 4; mi++)
#pragma unroll
      for (int ni = 0; ni < 4; ni++)
        acc[mi][ni] = __builtin_amdgcn_mfma_f32_16x16x32_bf16(af[mi].s, bfx[ni].s, acc[mi][ni], 0, 0, 0);
  }
  // D frag: col(lane&15) -> f, row(quad*4+r) -> i; write transposed
#pragma unroll
  for (int mi = 0; mi < 4; mi++) {
    long long m0 = mbase + wm + mi * 16 + quad * 4;
    int bb = (int)(m0 >> 9);
    int ir = (int)(m0 & 511);
#pragma unroll
    for (int ni = 0; ni < 4; ni++) {
      int f = nbase + wn + ni * 16 + lrow;
      U8 w;
#pragma unroll
      for (int r = 0; r < 4; r++) w.h[r] = (bf16)acc[mi][ni][r];
      *(ushort4*)(outT + (((long long)h * 32 + bb) * 256 + f) * 512 + ir) = w.s;
    }
  }
}

// ---- kernel 4: f1' = (Wh·a1)*log2e, f2' likewise (reads WhT) ------------
__global__ __launch_bounds__(256) void k_f12(const bf16* __restrict__ WhT,
                                             const float* __restrict__ a1,
                                             const float* __restrict__ a2,
                                             float* __restrict__ f1p,
                                             float* __restrict__ f2p, int aStride) {
  __shared__ float s1[256], s2[256];
  const int hb = blockIdx.x, tid = threadIdx.x;
  s1[tid] = a1[(hb >> 5) * aStride + tid];
  s2[tid] = a2[(hb >> 5) * aStride + tid];
  __syncthreads();
  const bf16* wt = WhT + (long long)hb * 256 * 512;
  const int i0 = tid * 2;
  float r1a = 0.f, r1b = 0.f, r2a = 0.f, r2b = 0.f;
  for (int f = 0; f < 256; f++) {
    union { uint u; bf16 h[2]; } w;
    w.u = *(const uint*)(wt + f * 512 + i0);
    float wa = (float)w.h[0], wb = (float)w.h[1];
    r1a += wa * s1[f]; r1b += wb * s1[f];
    r2a += wa * s2[f]; r2b += wb * s2[f];
  }
  f1p[hb * 512 + i0]     = r1a * LOG2E;
  f1p[hb * 512 + i0 + 1] = r1b * LOG2E;
  f2p[hb * 512 + i0]     = r2a * LOG2E;
  f2p[hb * 512 + i0 + 1] = r2b * LOG2E;
}

// ---- kernel 5: softmax constants c_i = M_i + log2(d_i) ------------------
__global__ __launch_bounds__(256) void k_passA(const float* __restrict__ f1p,
                                               const float* __restrict__ f2p,
                                               const unsigned long long* __restrict__ mask,
                                               float* __restrict__ cc) {
  const int hb = blockIdx.x, bb = hb & 31;
  const int wave = threadIdx.x >> 6, lane = threadIdx.x & 63;
  const int i = blockIdx.y * 4 + wave;
  const float* f2 = f2p + hb * 512;
  float4 va = *(const float4*)(f2 + lane * 8);
  float4 vb = *(const float4*)(f2 + lane * 8 + 4);
  float vj[8] = {va.x, va.y, va.z, va.w, vb.x, vb.y, vb.z, vb.w};
  unsigned int mb = ((const unsigned char*)(mask + ((long long)bb * 512 + i) * 8))[lane];
  float f1 = f1p[hb * 512 + i];
  float m = -INFINITY;
#pragma unroll
  for (int t = 0; t < 8; t++)
    if ((mb >> t) & 1) m = fmaxf(m, vj[t]);
#pragma unroll
  for (int off = 32; off; off >>= 1) m = fmaxf(m, __shfl_xor(m, off));
  float s = f1 + m;
  float M = fmaxf(s, 0.2f * s);
  float d = 0.f;
#pragma unroll
  for (int t = 0; t < 8; t++) {
    float e0 = f1 + vj[t];
    float e = fmaxf(e0, 0.2f * e0);
    float p = exp2f(e - M);
    d += ((mb >> t) & 1) ? p : 0.f;
  }
#pragma unroll
  for (int off = 32; off; off >>= 1) d += __shfl_xor(d, off);
  if (lane == 0) {
    float cv = M + log2f(d);
    if (!isfinite(M) || !(d > 0.f)) cv = INFINITY;  // fully-masked row -> P=0
    cc[hb * 512 + i] = cv;
  }
}

// ---- kernel 6: fused masked-softmax PV (flash-style, scores are rank-1) -
template <int NH, bool FINAL>
__global__ __launch_bounds__(256) void k_pv(const bf16* __restrict__ WhT,
                                            const float* __restrict__ f1p,
                                            const float* __restrict__ cc,
                                            const float* __restrict__ f2p,
                                            const unsigned long long* __restrict__ mask,
                                            void* __restrict__ outv) {
  constexpr int PH = 258;
  __shared__ float hsum[32 * PH];
  __shared__ float f2s[512];
  __shared__ unsigned char ms[32 * 64];
  const int id = blockIdx.x;
  const int bb = id & 31, it = id >> 5;
  const int ibase = it * 32;
  const int tid = threadIdx.x, wave = tid >> 6, lane = tid & 63;
  const int lrow = lane & 15, quad = lane >> 4;
  for (int t = tid; t < 32 * PH; t += 256) hsum[t] = 0.f;
  {
    const uint4* msrc = (const uint4*)(mask + ((long long)bb * 512 + ibase) * 8);
    uint4* mdst = (uint4*)ms;
    if (tid < 128) mdst[tid] = msrc[tid];
  }
  for (int h = 0; h < NH; h++) {
    const int hb = h * 32 + bb;
    __syncthreads();
    for (int t = tid; t < 512; t += 256) f2s[t] = f2p[hb * 512 + t];
    __syncthreads();
    float f1l[2], cl[2];
#pragma unroll
    for (int mi = 0; mi < 2; mi++) {
      int i = ibase + mi * 16 + lrow;
      f1l[mi] = f1p[hb * 512 + i];
      cl[mi]  = cc[hb * 512 + i];
    }
    const bf16* wt = WhT + (long long)hb * 256 * 512;
    f32x4 acc[2][4];
#pragma unroll
    for (int i = 0; i < 2; i++)
#pragma unroll
      for (int j = 0; j < 4; j++) acc[i][j] = {0.f, 0.f, 0.f, 0.f};
    const int fcol = wave * 64 + lrow;
    for (int j0 = 0; j0 < 512; j0 += 32) {
      V16 bfr[4];
#pragma unroll
      for (int ni = 0; ni < 4; ni++)
        bfr[ni].u = *(const uint4*)(wt + (long long)(fcol + ni * 16) * 512 + j0 + quad * 8);
      float fj[8];
      {
        float4 u0 = *(const float4*)(f2s + j0 + quad * 8);
        float4 u1 = *(const float4*)(f2s + j0 + quad * 8 + 4);
        fj[0] = u0.x; fj[1] = u0.y; fj[2] = u0.z; fj[3] = u0.w;
        fj[4] = u1.x; fj[5] = u1.y; fj[6] = u1.z; fj[7] = u1.w;
      }
#pragma unroll
      for (int mi = 0; mi < 2; mi++) {
        unsigned int mb = ms[(mi * 16 + lrow) * 64 + (j0 >> 3) + quad];
        V16 af;
        float f1v = f1l[mi], cv = cl[mi];
#pragma unroll
        for (int t = 0; t < 8; t++) {
          float s = f1v + fj[t];
          float e = fmaxf(s, 0.2f * s);
          float p = ((mb >> t) & 1) ? exp2f(e - cv) : 0.f;
          af.h[t] = (bf16)p;                // P directly in A-frag layout
        }
#pragma unroll
        for (int ni = 0; ni < 4; ni++)
          acc[mi][ni] = __builtin_amdgcn_mfma_f32_16x16x32_bf16(af.s, bfr[ni].s, acc[mi][ni], 0, 0, 0);
      }
    }
#pragma unroll
    for (int mi = 0; mi < 2; mi++) {
      int il = mi * 16 + quad * 4;
#pragma unroll
      for (int ni = 0; ni < 4; ni++) {
        int f = wave * 64 + ni * 16 + lrow;
#pragma unroll
        for (int r = 0; r < 4; r++) {
          float v = acc[mi][ni][r];
          float u;
          if (FINAL) u = v;
          else u = (v > 0.f ? v : (exp2f(v * LOG2E) - 1.f)) * 0.125f; // elu/8
          hsum[(il + r) * PH + f] += u;
        }
      }
    }
  }
  __syncthreads();
  const int i = tid >> 3, fb = (tid & 7) * 32;
  if (FINAL) {
    float* op = (float*)outv + (((long long)bb * 512) + ibase + i) * 256 + fb;
    for (int c0 = 0; c0 < 32; c0 += 4) {
      float4 w;
      w.x = fmaxf(hsum[i * PH + fb + c0 + 0], 0.f);
      w.y = fmaxf(hsum[i * PH + fb + c0 + 1], 0.f);
      w.z = fmaxf(hsum[i * PH + fb + c0 + 2], 0.f);
      w.w = fmaxf(hsum[i * PH + fb + c0 + 3], 0.f);
      *(float4*)(op + c0) = w;
    }
  } else {
    bf16* op = (bf16*)outv + (((long long)bb * 512) + ibase + i) * 256 + fb;
    for (int c0 = 0; c0 < 32; c0 += 4) {
      U8 w;
#pragma unroll
      for (int r = 0; r < 4; r++) w.h[r] = (bf16)hsum[i * PH + fb + c0 + r];
      *(ushort4*)(op + c0) = w.s;
    }
  }
}

extern "C" void kernel_launch(void* const* d_in, const int* in_sizes, int n_in,
                              void* d_out, int out_size, void* d_ws, size_t ws_size,
                              hipStream_t stream) {
  const float* x    = (const float*)d_in[0];
  const int*   adj  = (const int*)d_in[1];
  const float* W0   = (const float*)d_in[2];
  const float* a1_0 = (const float*)d_in[3];
  const float* a2_0 = (const float*)d_in[4];
  const float* Wo   = (const float*)d_in[5];
  const float* a1_o = (const float*)d_in[6];
  const float* a2_o = (const float*)d_in[7];

  char* p = (char*)d_ws;
  auto take = [&](size_t n) { char* r = p; p += (n + 255) & ~(size_t)255; return r; };
  unsigned long long* maskb = (unsigned long long*)take(32ull * 512 * 8 * 8);
  bf16*  xb   = (bf16*)take(32ull * 512 * 768 * 2);
  bf16*  W0T  = (bf16*)take(8ull * 256 * 768 * 2);
  bf16*  WoT  = (bf16*)take(256ull * 256 * 2);
  bf16*  WhT  = (bf16*)take(8ull * 32 * 256 * 512 * 2);
  float* f1p1 = (float*)take(8ull * 32 * 512 * 4);
  float* f2p1 = (float*)take(8ull * 32 * 512 * 4);
  float* c1   = (float*)take(8ull * 32 * 512 * 4);
  float* f1p2 = (float*)take(32ull * 512 * 4);
  float* f2p2 = (float*)take(32ull * 512 * 4);
  float* c2   = (float*)take(32ull * 512 * 4);
  bf16* hmid = xb;    // xb dead after layer-1 GEMM; reuse for h_mid
  bf16* Wh2T = WhT;   // WhT dead after pv1; reuse for layer-2

  k_cvt<<<6144, 256, 0, stream>>>(x, xb, 32ll * 512 * 768);
  k_maskpack<<<32768, 256, 0, stream>>>(adj, maskb);
  k_transpose<<<dim3(8, 24, 8), 256, 0, stream>>>(W0, W0T, 768, 256);
  k_transpose<<<dim3(8, 8, 1), 256, 0, stream>>>(Wo, WoT, 256, 256);
  // layer 1
  k_gemm<<<dim3(2, 128, 8), 256, 0, stream>>>(xb, W0T, WhT, 768);
  k_f12<<<256, 256, 0, stream>>>(WhT, a1_0, a2_0, f1p1, f2p1, 256);
  k_passA<<<dim3(256, 128), 256, 0, stream>>>(f1p1, f2p1, maskb, c1);
  k_pv<8, false><<<512, 256, 0, stream>>>(WhT, f1p1, c1, f2p1, maskb, hmid);
  // layer 2
  k_gemm<<<dim3(2, 128, 1), 256, 0, stream>>>(hmid, WoT, Wh2T, 256);
  k_f12<<<32, 256, 0, stream>>>(Wh2T, a1_o, a2_o, f1p2, f2p2, 0);
  k_passA<<<dim3(32, 128), 256, 0, stream>>>(f1p2, f2p2, maskb, c2);
  k_pv<1, true><<<512, 256, 0, stream>>>(Wh2T, f1p2, c2, f2p2, maskb, d_out);
}

// Round 4
// 465.798 us; speedup vs baseline: 1.0223x; 1.0223x over previous
//
#include <hip/hip_runtime.h>
#include <hip/hip_bf16.h>
#include <stdint.h>

typedef __bf16 bf16;
typedef short short8 __attribute__((ext_vector_type(8)));   // bf16 A/B frag (bit pattern)
typedef float f32x4 __attribute__((ext_vector_type(4)));

#define LOG2E 1.4426950408889634f

union V16 { uint4 u; short8 s; bf16 h[8]; };
union U8  { ushort4 s; bf16 h[4]; };

// ---- kernel 0: f32 -> bf16 bulk convert (n multiple of 8) ---------------
__global__ __launch_bounds__(256) void k_cvt(const float* __restrict__ src,
                                             bf16* __restrict__ dst, long long n) {
  long long i = ((long long)blockIdx.x * 256 + threadIdx.x) * 8;
  if (i >= n) return;
  float4 a = *(const float4*)(src + i);
  float4 b = *(const float4*)(src + i + 4);
  U8 w0, w1;
  w0.h[0] = (bf16)a.x; w0.h[1] = (bf16)a.y; w0.h[2] = (bf16)a.z; w0.h[3] = (bf16)a.w;
  w1.h[0] = (bf16)b.x; w1.h[1] = (bf16)b.y; w1.h[2] = (bf16)b.z; w1.h[3] = (bf16)b.w;
  *(ushort4*)(dst + i)     = w0.s;
  *(ushort4*)(dst + i + 4) = w1.s;
}

// ---- kernel 1: pack adjacency rows into 512-bit masks (ballot trick) ----
__global__ __launch_bounds__(256) void k_maskpack(const int* __restrict__ adj,
                                                  unsigned long long* __restrict__ mask) {
  int wid = blockIdx.x * 4 + (threadIdx.x >> 6);
  int lane = threadIdx.x & 63;
  int a = adj[(long long)wid * 64 + lane];
  unsigned long long m = __ballot(a > 0);
  if (lane == 0) mask[wid] = m;
}

// ---- kernel 2: f32 [R,C] -> bf16 [C,R] transpose+convert per z-slice ----
__global__ __launch_bounds__(256) void k_transpose(const float* __restrict__ src,
                                                   bf16* __restrict__ dst, int R, int C) {
  __shared__ float t[32][33];
  int c0 = blockIdx.x * 32, r0 = blockIdx.y * 32;
  src += (long long)blockIdx.z * R * C;
  dst += (long long)blockIdx.z * R * C;
  int tx = threadIdx.x & 31, ty = threadIdx.x >> 5;
  for (int rr = ty; rr < 32; rr += 8)
    t[rr][tx] = src[(long long)(r0 + rr) * C + (c0 + tx)];
  __syncthreads();
  for (int cc = ty; cc < 32; cc += 8)
    dst[(long long)(c0 + cc) * R + (r0 + tx)] = (bf16)t[tx][cc];
}

// ---- kernel 3: bf16 MFMA GEMM, transposed output ------------------------
// outT[(h*32+b)*256 + f][i] = sum_k A[m=b*512+i][k] * WT[h][f][k]
__global__ __launch_bounds__(256) void k_gemm(const bf16* __restrict__ A,
                                              const bf16* __restrict__ WT,
                                              bf16* __restrict__ outT, int K) {
  constexpr int PK = 40;
  __shared__ bf16 As[128 * PK];
  __shared__ bf16 Bs[128 * PK];
  const int nb = blockIdx.x, mb = blockIdx.y, h = blockIdx.z;
  const int tid = threadIdx.x, wave = tid >> 6, lane = tid & 63;
  const int lrow = lane & 15, quad = lane >> 4;
  const long long mbase = (long long)mb * 128;
  const int nbase = nb * 128;
  const bf16* W = WT + (long long)h * 256 * K;
  const int wm = (wave >> 1) * 64, wn = (wave & 1) * 64;
  const int srow = tid >> 1, skoff = (tid & 1) * 16;
  const bf16* ag = A + (mbase + srow) * K + skoff;
  const bf16* bg = W + (long long)(nbase + srow) * K + skoff;
  f32x4 acc[4][4];
#pragma unroll
  for (int i = 0; i < 4; i++)
#pragma unroll
    for (int j = 0; j < 4; j++) acc[i][j] = {0.f, 0.f, 0.f, 0.f};
  for (int k0 = 0; k0 < K; k0 += 32) {
    uint4 a0 = *(const uint4*)(ag + k0);
    uint4 a1 = *(const uint4*)(ag + k0 + 8);
    uint4 b0 = *(const uint4*)(bg + k0);
    uint4 b1 = *(const uint4*)(bg + k0 + 8);
    __syncthreads();
    *(uint4*)(As + srow * PK + skoff)     = a0;
    *(uint4*)(As + srow * PK + skoff + 8) = a1;
    *(uint4*)(Bs + srow * PK + skoff)     = b0;
    *(uint4*)(Bs + srow * PK + skoff + 8) = b1;
    __syncthreads();
    V16 af[4], bfx[4];
#pragma unroll
    for (int mi = 0; mi < 4; mi++)
      af[mi].u = *(const uint4*)(As + (wm + mi * 16 + lrow) * PK + quad * 8);
#pragma unroll
    for (int ni = 0; ni < 4; ni++)
      bfx[ni].u = *(const uint4*)(Bs + (wn + ni * 16 + lrow) * PK + quad * 8);
#pragma unroll
    for (int mi = 0; mi < 4; mi++)
#pragma unroll
      for (int ni = 0; ni < 4; ni++)
        acc[mi][ni] = __builtin_amdgcn_mfma_f32_16x16x32_bf16(af[mi].s, bfx[ni].s, acc[mi][ni], 0, 0, 0);
  }
  // D frag: col(lane&15) -> f, row(quad*4+r) -> i; write transposed
#pragma unroll
  for (int mi = 0; mi < 4; mi++) {
    long long m0 = mbase + wm + mi * 16 + quad * 4;
    int bb = (int)(m0 >> 9);
    int ir = (int)(m0 & 511);
#pragma unroll
    for (int ni = 0; ni < 4; ni++) {
      int f = nbase + wn + ni * 16 + lrow;
      U8 w;
#pragma unroll
      for (int r = 0; r < 4; r++) w.h[r] = (bf16)acc[mi][ni][r];
      *(ushort4*)(outT + (((long long)h * 32 + bb) * 256 + f) * 512 + ir) = w.s;
    }
  }
}

// ---- kernel 4: f1' = (Wh·a1)*log2e, f2' likewise (reads WhT) ------------
__global__ __launch_bounds__(256) void k_f12(const bf16* __restrict__ WhT,
                                             const float* __restrict__ a1,
                                             const float* __restrict__ a2,
                                             float* __restrict__ f1p,
                                             float* __restrict__ f2p, int aStride) {
  __shared__ float s1[256], s2[256];
  const int hb = blockIdx.x, tid = threadIdx.x;
  s1[tid] = a1[(hb >> 5) * aStride + tid];
  s2[tid] = a2[(hb >> 5) * aStride + tid];
  __syncthreads();
  const bf16* wt = WhT + (long long)hb * 256 * 512;
  const int i0 = tid * 2;
  float r1a = 0.f, r1b = 0.f, r2a = 0.f, r2b = 0.f;
  for (int f = 0; f < 256; f++) {
    union { uint u; bf16 h[2]; } w;
    w.u = *(const uint*)(wt + f * 512 + i0);
    float wa = (float)w.h[0], wb = (float)w.h[1];
    r1a += wa * s1[f]; r1b += wb * s1[f];
    r2a += wa * s2[f]; r2b += wb * s2[f];
  }
  f1p[hb * 512 + i0]     = r1a * LOG2E;
  f1p[hb * 512 + i0 + 1] = r1b * LOG2E;
  f2p[hb * 512 + i0]     = r2a * LOG2E;
  f2p[hb * 512 + i0 + 1] = r2b * LOG2E;
}

// ---- kernel 5: softmax constants c_i = M_i + log2(d_i) ------------------
__global__ __launch_bounds__(256) void k_passA(const float* __restrict__ f1p,
                                               const float* __restrict__ f2p,
                                               const unsigned long long* __restrict__ mask,
                                               float* __restrict__ cc) {
  const int hb = blockIdx.x, bb = hb & 31;
  const int wave = threadIdx.x >> 6, lane = threadIdx.x & 63;
  const int i = blockIdx.y * 4 + wave;
  const float* f2 = f2p + hb * 512;
  float4 va = *(const float4*)(f2 + lane * 8);
  float4 vb = *(const float4*)(f2 + lane * 8 + 4);
  float vj[8] = {va.x, va.y, va.z, va.w, vb.x, vb.y, vb.z, vb.w};
  unsigned int mb = ((const unsigned char*)(mask + ((long long)bb * 512 + i) * 8))[lane];
  float f1 = f1p[hb * 512 + i];
  float m = -INFINITY;
#pragma unroll
  for (int t = 0; t < 8; t++)
    if ((mb >> t) & 1) m = fmaxf(m, vj[t]);
#pragma unroll
  for (int off = 32; off; off >>= 1) m = fmaxf(m, __shfl_xor(m, off));
  float s = f1 + m;
  float M = fmaxf(s, 0.2f * s);
  float d = 0.f;
#pragma unroll
  for (int t = 0; t < 8; t++) {
    float e0 = f1 + vj[t];
    float e = fmaxf(e0, 0.2f * e0);
    float p = exp2f(e - M);
    d += ((mb >> t) & 1) ? p : 0.f;
  }
#pragma unroll
  for (int off = 32; off; off >>= 1) d += __shfl_xor(d, off);
  if (lane == 0) {
    float cv = M + log2f(d);
    if (!isfinite(M) || !(d > 0.f)) cv = INFINITY;  // fully-masked row -> P=0
    cc[hb * 512 + i] = cv;
  }
}

// ---- kernel 6: fused masked-softmax PV, cooperative-P version -----------
// Block = 32 i-rows x all 256 f. P (32x512) built ONCE per head by all 256
// threads into swizzled LDS; waves read A-frags from LDS; elu/mean
// accumulated in VGPRs across heads. grid 512 = it*32 + b (XCD swizzle).
union PvU { bf16 P[32 * 512]; float hs[32 * 264]; };

__device__ __forceinline__ int pchunk(int row, int c) {   // bf16 index of 8-elem chunk
  return row * 512 + (((c + 3 * row) & 63) << 3);
}

template <int NH, bool FINAL>
__global__ __launch_bounds__(256) void k_pv(const bf16* __restrict__ WhT,
                                            const float* __restrict__ f1p,
                                            const float* __restrict__ cc,
                                            const float* __restrict__ f2p,
                                            const unsigned long long* __restrict__ mask,
                                            void* __restrict__ outv) {
  __shared__ PvU sh;
  __shared__ unsigned char ms[32 * 64];
  const int id = blockIdx.x;
  const int bb = id & 31, it = id >> 5;
  const int ibase = it * 32;
  const int tid = threadIdx.x, wave = tid >> 6, lane = tid & 63;
  const int lrow = lane & 15, quad = lane >> 4;
  const int pi = tid >> 3;           // P row 0..31 (8 threads per row)
  const int pj = tid & 7;            // column-block owner within the row
  // stage masks once, build per-lane 8-byte register
  {
    const uint4* msrc = (const uint4*)(mask + ((long long)bb * 512 + ibase) * 8);
    if (tid < 128) ((uint4*)ms)[tid] = msrc[tid];
  }
  __syncthreads();
  unsigned long long mreg = 0;
#pragma unroll
  for (int t = 0; t < 8; t++)
    mreg |= (unsigned long long)ms[pi * 64 + pj + t * 8] << (t * 8);
  const int fcol = wave * 64 + lrow;
  f32x4 hacc[2][4];
#pragma unroll
  for (int i = 0; i < 2; i++)
#pragma unroll
    for (int j = 0; j < 4; j++) hacc[i][j] = {0.f, 0.f, 0.f, 0.f};

  for (int h = 0; h < NH; h++) {
    const int hb = h * 32 + bb;
    const float f1v = f1p[hb * 512 + ibase + pi];
    const float cv  = cc[hb * 512 + ibase + pi];
    const float Ac = f1v - cv;
    const float Bc = __builtin_fmaf(0.2f, f1v, -cv);
    const float* f2 = f2p + hb * 512;
    __syncthreads();                  // previous head's P reads complete
    // ---- cooperative P build: lane covers row pi, j = pj*8 + t*64 + [0,8)
#pragma unroll
    for (int t = 0; t < 8; t++) {
      const int j0 = pj * 8 + t * 64;
      float4 u0 = *(const float4*)(f2 + j0);
      float4 u1 = *(const float4*)(f2 + j0 + 4);
      float fj[8] = {u0.x, u0.y, u0.z, u0.w, u1.x, u1.y, u1.z, u1.w};
      unsigned int mb = (unsigned int)(mreg >> (t * 8)) & 0xff;
      V16 pk;
#pragma unroll
      for (int u = 0; u < 8; u++) {
        float e = fmaxf(fj[u] + Ac, __builtin_fmaf(0.2f, fj[u], Bc));
        float p = ((mb >> u) & 1) ? exp2f(e) : 0.f;
        pk.h[u] = (bf16)p;
      }
      *(uint4*)(sh.P + pchunk(pi, pj + t * 8)) = pk.u;
    }
    __syncthreads();
    // ---- MFMA phase: A-frags from LDS, B-frags from global (L2-hot)
    const bf16* wt = WhT + (long long)hb * 256 * 512;
    f32x4 acc[2][4];
#pragma unroll
    for (int i = 0; i < 2; i++)
#pragma unroll
      for (int j = 0; j < 4; j++) acc[i][j] = {0.f, 0.f, 0.f, 0.f};
    for (int js = 0; js < 16; js++) {
      V16 a0, a1, bfr[4];
      a0.u = *(const uint4*)(sh.P + pchunk(lrow,      js * 4 + quad));
      a1.u = *(const uint4*)(sh.P + pchunk(16 + lrow, js * 4 + quad));
#pragma unroll
      for (int ni = 0; ni < 4; ni++)
        bfr[ni].u = *(const uint4*)(wt + (long long)(fcol + ni * 16) * 512 + js * 32 + quad * 8);
#pragma unroll
      for (int ni = 0; ni < 4; ni++) {
        acc[0][ni] = __builtin_amdgcn_mfma_f32_16x16x32_bf16(a0.s, bfr[ni].s, acc[0][ni], 0, 0, 0);
        acc[1][ni] = __builtin_amdgcn_mfma_f32_16x16x32_bf16(a1.s, bfr[ni].s, acc[1][ni], 0, 0, 0);
      }
    }
    // ---- per-head epilogue in registers
#pragma unroll
    for (int mi = 0; mi < 2; mi++)
#pragma unroll
      for (int ni = 0; ni < 4; ni++)
#pragma unroll
        for (int r = 0; r < 4; r++) {
          float v = acc[mi][ni][r];
          hacc[mi][ni][r] += FINAL ? v
                                   : (v > 0.f ? v : (exp2f(v * LOG2E) - 1.f));
        }
  }
  __syncthreads();
  // ---- stash hacc into LDS (pitch 264: 2-way max) then coalesced writeback
#pragma unroll
  for (int mi = 0; mi < 2; mi++)
#pragma unroll
    for (int ni = 0; ni < 4; ni++) {
      int f = wave * 64 + ni * 16 + lrow;
#pragma unroll
      for (int r = 0; r < 4; r++) {
        int row = mi * 16 + quad * 4 + r;
        sh.hs[row * 264 + f] = hacc[mi][ni][r] * (FINAL ? 1.f : 0.125f);
      }
    }
  __syncthreads();
  const int fb = pj * 32;
  if (FINAL) {
    float* op = (float*)outv + (((long long)bb * 512) + ibase + pi) * 256 + fb;
    for (int c0 = 0; c0 < 32; c0 += 4) {
      float4 w;
      w.x = fmaxf(sh.hs[pi * 264 + fb + c0 + 0], 0.f);
      w.y = fmaxf(sh.hs[pi * 264 + fb + c0 + 1], 0.f);
      w.z = fmaxf(sh.hs[pi * 264 + fb + c0 + 2], 0.f);
      w.w = fmaxf(sh.hs[pi * 264 + fb + c0 + 3], 0.f);
      *(float4*)(op + c0) = w;
    }
  } else {
    bf16* op = (bf16*)outv + (((long long)bb * 512) + ibase + pi) * 256 + fb;
    for (int c0 = 0; c0 < 32; c0 += 4) {
      U8 w;
#pragma unroll
      for (int r = 0; r < 4; r++) w.h[r] = (bf16)sh.hs[pi * 264 + fb + c0 + r];
      *(ushort4*)(op + c0) = w.s;
    }
  }
}

extern "C" void kernel_launch(void* const* d_in, const int* in_sizes, int n_in,
                              void* d_out, int out_size, void* d_ws, size_t ws_size,
                              hipStream_t stream) {
  const float* x    = (const float*)d_in[0];
  const int*   adj  = (const int*)d_in[1];
  const float* W0   = (const float*)d_in[2];
  const float* a1_0 = (const float*)d_in[3];
  const float* a2_0 = (const float*)d_in[4];
  const float* Wo   = (const float*)d_in[5];
  const float* a1_o = (const float*)d_in[6];
  const float* a2_o = (const float*)d_in[7];

  char* p = (char*)d_ws;
  auto take = [&](size_t n) { char* r = p; p += (n + 255) & ~(size_t)255; return r; };
  unsigned long long* maskb = (unsigned long long*)take(32ull * 512 * 8 * 8);
  bf16*  xb   = (bf16*)take(32ull * 512 * 768 * 2);
  bf16*  W0T  = (bf16*)take(8ull * 256 * 768 * 2);
  bf16*  WoT  = (bf16*)take(256ull * 256 * 2);
  bf16*  WhT  = (bf16*)take(8ull * 32 * 256 * 512 * 2);
  float* f1p1 = (float*)take(8ull * 32 * 512 * 4);
  float* f2p1 = (float*)take(8ull * 32 * 512 * 4);
  float* c1   = (float*)take(8ull * 32 * 512 * 4);
  float* f1p2 = (float*)take(32ull * 512 * 4);
  float* f2p2 = (float*)take(32ull * 512 * 4);
  float* c2   = (float*)take(32ull * 512 * 4);
  bf16* hmid = xb;    // xb dead after layer-1 GEMM; reuse for h_mid
  bf16* Wh2T = WhT;   // WhT dead after pv1; reuse for layer-2

  k_cvt<<<6144, 256, 0, stream>>>(x, xb, 32ll * 512 * 768);
  k_maskpack<<<32768, 256, 0, stream>>>(adj, maskb);
  k_transpose<<<dim3(8, 24, 8), 256, 0, stream>>>(W0, W0T, 768, 256);
  k_transpose<<<dim3(8, 8, 1), 256, 0, stream>>>(Wo, WoT, 256, 256);
  // layer 1
  k_gemm<<<dim3(2, 128, 8), 256, 0, stream>>>(xb, W0T, WhT, 768);
  k_f12<<<256, 256, 0, stream>>>(WhT, a1_0, a2_0, f1p1, f2p1, 256);
  k_passA<<<dim3(256, 128), 256, 0, stream>>>(f1p1, f2p1, maskb, c1);
  k_pv<8, false><<<512, 256, 0, stream>>>(WhT, f1p1, c1, f2p1, maskb, hmid);
  // layer 2
  k_gemm<<<dim3(2, 128, 1), 256, 0, stream>>>(hmid, WoT, Wh2T, 256);
  k_f12<<<32, 256, 0, stream>>>(Wh2T, a1_o, a2_o, f1p2, f2p2, 0);
  k_passA<<<dim3(32, 128), 256, 0, stream>>>(f1p2, f2p2, maskb, c2);
  k_pv<1, true><<<512, 256, 0, stream>>>(Wh2T, f1p2, c2, f2p2, maskb, d_out);
}